// Round 2
// baseline (716.210 us; speedup 1.0000x reference)
//
#include <hip/hip_runtime.h>
#include <hip/hip_bf16.h>

typedef unsigned short u16;
using f32x4  = __attribute__((ext_vector_type(4))) float;
using bf16x8 = __attribute__((ext_vector_type(8))) short;

typedef __attribute__((address_space(1))) const void global_cvoid;
typedef __attribute__((address_space(3))) void lds_void;

__device__ __forceinline__ void async16(const u16* g, u16* l) {
    // direct global->LDS DMA, 16B per lane, LDS dest = wave-uniform base + lane*16
    __builtin_amdgcn_global_load_lds((global_cvoid*)g, (lds_void*)l, 16, 0, 0);
}

__device__ __forceinline__ u16 f2bf(float f) {
    union { float f; unsigned u; } cv; cv.f = f;
    unsigned r = cv.u + 0x7fff + ((cv.u >> 16) & 1);   // RNE
    return (u16)(r >> 16);
}

// ---------------- cast fp32 -> bf16 (vectorized, memory-bound) ----------------
__global__ __launch_bounds__(256) void cast_kernel(const float* __restrict__ src,
                                                   u16* __restrict__ dst, int n4) {
    int i = blockIdx.x * blockDim.x + threadIdx.x;
    int st = gridDim.x * blockDim.x;
    for (; i < n4; i += st) {
        float4 v = ((const float4*)src)[i];
        ushort4 o;
        o.x = f2bf(v.x); o.y = f2bf(v.y); o.z = f2bf(v.z); o.w = f2bf(v.w);
        ((ushort4*)dst)[i] = o;
    }
}

// ---------------- transpose + cast: fp32 [R][C] -> bf16 [C][R] ----------------
__global__ __launch_bounds__(256) void wtrans_kernel(const float* __restrict__ src,
                                                     u16* __restrict__ dst, int R, int C) {
    __shared__ float tile[64][68];
    int ct = blockIdx.x, rt = blockIdx.y;
    int t = threadIdx.x;
    int r = t >> 2;
    const float* s = src + (size_t)(rt * 64 + r) * C + ct * 64;
#pragma unroll
    for (int jj = 0; jj < 4; ++jj) {
        int c4 = (t & 3) + jj * 4;
        float4 v = *(const float4*)(s + c4 * 4);
        *(float4*)&tile[r][c4 * 4] = v;
    }
    __syncthreads();
    int od = t >> 2;
    u16* d = dst + (size_t)(ct * 64 + od) * R + rt * 64;
#pragma unroll
    for (int jj = 0; jj < 4; ++jj) {
        int c4 = (t & 3) + jj * 4;
        ushort4 v;
        v.x = f2bf(tile[c4 * 4 + 0][od]);
        v.y = f2bf(tile[c4 * 4 + 1][od]);
        v.z = f2bf(tile[c4 * 4 + 2][od]);
        v.w = f2bf(tile[c4 * 4 + 3][od]);
        *(ushort4*)(d + c4 * 4) = v;
    }
}

// ------------- V transpose (bf16->bf16): per (b,h) [1024][192] -> [192][1024] -------------
__global__ __launch_bounds__(256) void vtrans_kernel(const u16* __restrict__ QKV,
                                                     u16* __restrict__ VT) {
    __shared__ u16 tile[64][72];
    int kt = blockIdx.x, dt = blockIdx.y, bh = blockIdx.z;
    int b = bh >> 4, h = bh & 15;
    int t = threadIdx.x;
    int r = t >> 2;
    const u16* src = QKV + ((size_t)(b * 3072 + 2048 + kt * 64)) * 3072 + h * 192 + dt * 64;
#pragma unroll
    for (int jj = 0; jj < 4; ++jj) {
        int c4 = (t & 3) + jj * 4;
        ushort4 v = *(const ushort4*)(src + (size_t)r * 3072 + c4 * 4);
        *(ushort4*)&tile[r][c4 * 4] = v;
    }
    __syncthreads();
    int od = t >> 2;
    u16* dst = VT + ((size_t)(bh * 192 + dt * 64 + od)) * 1024 + kt * 64;
#pragma unroll
    for (int jj = 0; jj < 4; ++jj) {
        int c4 = (t & 3) + jj * 4;
        ushort4 v;
        v.x = tile[c4 * 4 + 0][od];
        v.y = tile[c4 * 4 + 1][od];
        v.z = tile[c4 * 4 + 2][od];
        v.w = tile[c4 * 4 + 3][od];
        *(ushort4*)(dst + c4 * 4) = v;
    }
}

// ---------------- 128x128 bf16 GEMM, B^T input (m97 structure) ----------------
template<bool OUT_F32>
__global__ __launch_bounds__(256, 2)
void gemm_bt_kernel(const u16* __restrict__ A, const u16* __restrict__ BT,
                    void* __restrict__ Cout, const float* __restrict__ bias,
                    int M, int N, int K) {
    __shared__ u16 lA[128 * 64];
    __shared__ u16 lB[128 * 64];
    const int t = threadIdx.x;
    const int w = t >> 6, lane = t & 63;
    const int nbx = N >> 7;
    const int nwg = gridDim.x;
    int bid = blockIdx.x;
    int cpx = nwg >> 3;
    int swz = (bid & 7) * cpx + (bid >> 3);
    const int bx = swz % nbx;
    const int by = swz / nbx;
    const size_t m0 = (size_t)by * 128, n0 = (size_t)bx * 128;

    const int lr = lane >> 3;
    const int lc = (lane & 7) * 8;
    const int wr = (w >> 1) * 64, wc = (w & 1) * 64;

    f32x4 acc[4][4] = {};

    for (int kk = 0; kk < K; kk += 64) {
        __syncthreads();
#pragma unroll
        for (int i = 0; i < 4; ++i) {
            int rr = (w * 4 + i) * 8 + lr;
            async16(A  + (m0 + rr) * (size_t)K + kk + lc, &lA[(w * 4 + i) * 512]);
            async16(BT + (n0 + rr) * (size_t)K + kk + lc, &lB[(w * 4 + i) * 512]);
        }
        __syncthreads();
#pragma unroll
        for (int ks = 0; ks < 2; ++ks) {
            bf16x8 af[4], bfv[4];
#pragma unroll
            for (int m = 0; m < 4; ++m)
                af[m] = *(const bf16x8*)&lA[(wr + m * 16 + (lane & 15)) * 64 + ks * 32 + (lane >> 4) * 8];
#pragma unroll
            for (int n = 0; n < 4; ++n)
                bfv[n] = *(const bf16x8*)&lB[(wc + n * 16 + (lane & 15)) * 64 + ks * 32 + (lane >> 4) * 8];
#pragma unroll
            for (int m = 0; m < 4; ++m)
#pragma unroll
                for (int n = 0; n < 4; ++n)
                    acc[m][n] = __builtin_amdgcn_mfma_f32_16x16x32_bf16(af[m], bfv[n], acc[m][n], 0, 0, 0);
        }
    }

    const int r0 = (lane >> 4) * 4;
    const int cl = lane & 15;
    if constexpr (OUT_F32) {
        float* C = (float*)Cout;
#pragma unroll
        for (int m = 0; m < 4; ++m) {
            size_t row = m0 + wr + m * 16 + r0;
#pragma unroll
            for (int n = 0; n < 4; ++n) {
                size_t col = n0 + wc + n * 16 + cl;
                float bv = bias[col];
#pragma unroll
                for (int r = 0; r < 4; ++r)
                    C[(row + r) * (size_t)N + col] = acc[m][n][r] + bv;
            }
        }
    } else {
        u16* C = (u16*)Cout;
#pragma unroll
        for (int m = 0; m < 4; ++m) {
            size_t row = m0 + wr + m * 16 + r0;
#pragma unroll
            for (int n = 0; n < 4; ++n) {
                size_t col = n0 + wc + n * 16 + cl;
#pragma unroll
                for (int r = 0; r < 4; ++r)
                    C[(row + r) * (size_t)N + col] = f2bf(acc[m][n][r]);
            }
        }
    }
}

// ---------------- flash attention v2 ----------------
// 8 waves x 32 q-rows = 256-row q-tile; Q fragments direct global->VGPR;
// K/V double-buffered in LDS with XOR-swizzle (pre-swizzled global source,
// linear global_load_lds dest, swizzled ds_read). One barrier per KV tile.
__global__ __launch_bounds__(512, 1)
void attn_kernel(const u16* __restrict__ QKV, const u16* __restrict__ VT,
                 u16* __restrict__ comb) {
    // 131072 B LDS: K0 | V0 | K1 | V1 (24KB each) | P (32KB, per-wave 4KB)
    __shared__ u16 lds[65536];
    u16* lK0 = lds;
    u16* lV0 = lds + 12288;
    u16* lK1 = lds + 24576;
    u16* lV1 = lds + 36864;
    u16* lP  = lds + 49152;

    const int t = threadIdx.x, w = t >> 6, lane = t & 63;
    const int bid = blockIdx.x;
    const int gid = (bid & 7) * 64 + (bid >> 3);      // XCD-chunked: 4 q-tiles of a bh share an XCD
    const int bh = gid >> 2, qt = gid & 3;
    const int b = bh >> 4, h = bh & 15;

    const u16* Qg  = QKV + ((size_t)(b * 3072 + qt * 256 + w * 32)) * 3072 + h * 192;
    const u16* Kg  = QKV + ((size_t)(b * 3072 + 1024)) * 3072 + h * 192;
    const u16* VTg = VT + (size_t)bh * 192 * 1024;

    // staging source addresses (iteration-invariant, pre-swizzled: rule #21)
    const u16* Ksrc[3];
    const u16* Vsrc[3];
#pragma unroll
    for (int i = 0; i < 3; ++i) {
        int ch = i * 512 + t;
        int kr = ch / 24, kc = ch % 24;               // K tile: 64 rows x 24 16B-chunks
        Ksrc[i] = Kg + (size_t)kr * 3072 + (kc ^ (kr & 7)) * 8;
        int vr = ch >> 3, vc = ch & 7;                // V tile: 192 rows x 8 16B-chunks
        Vsrc[i] = VTg + (size_t)vr * 1024 + (vc ^ (vr & 7)) * 8;
    }

#define STAGE(dK, dV, kt) do {                                               \
    _Pragma("unroll")                                                        \
    for (int i = 0; i < 3; ++i) {                                            \
        async16(Ksrc[i] + (size_t)(kt) * 196608, (dK) + (i * 512 + w * 64) * 8); \
        async16(Vsrc[i] + (size_t)(kt) * 64,     (dV) + (i * 512 + w * 64) * 8); \
    } } while (0)

    STAGE(lK0, lV0, 0);

    // Q fragments: direct global->VGPR (coalesces to 64B lines per row)
    bf16x8 aq[2][6];
#pragma unroll
    for (int rg = 0; rg < 2; ++rg)
#pragma unroll
        for (int cs = 0; cs < 6; ++cs)
            aq[rg][cs] = *(const bf16x8*)(Qg + (size_t)(rg * 16 + (lane & 15)) * 3072
                                             + cs * 32 + (lane >> 4) * 8);

    f32x4 acc_o[2][12] = {};
    float m2[2][4], lsum[2][4];
#pragma unroll
    for (int rg = 0; rg < 2; ++rg)
#pragma unroll
        for (int r = 0; r < 4; ++r) { m2[rg][r] = -1e30f; lsum[rg][r] = 0.f; }
    const float SC = 0.125f * 1.4426950408889634f;    // scale * log2(e)
    u16* lPw = &lP[w * 2048];

    auto compute = [&](const u16* lKc, const u16* lVc) {
        // S = Q K^T : B-fragments shared across both row-groups (in-register reuse)
        f32x4 s[2][4] = {};
#pragma unroll
        for (int kf = 0; kf < 4; ++kf) {
            const int krow = kf * 16 + (lane & 15);
#pragma unroll
            for (int cs = 0; cs < 6; ++cs) {
                bf16x8 bk = *(const bf16x8*)&lKc[krow * 192 + ((cs * 4 + (lane >> 4)) ^ (krow & 7)) * 8];
                s[0][kf] = __builtin_amdgcn_mfma_f32_16x16x32_bf16(aq[0][cs], bk, s[0][kf], 0, 0, 0);
                s[1][kf] = __builtin_amdgcn_mfma_f32_16x16x32_bf16(aq[1][cs], bk, s[1][kf], 0, 0, 0);
            }
        }
        // online softmax + P write (swizzled per-wave P buffer)
#pragma unroll
        for (int rg = 0; rg < 2; ++rg) {
#pragma unroll
            for (int kf = 0; kf < 4; ++kf) s[rg][kf] *= SC;
            float fac[4];
#pragma unroll
            for (int r = 0; r < 4; ++r) {
                float mx = fmaxf(fmaxf(s[rg][0][r], s[rg][1][r]), fmaxf(s[rg][2][r], s[rg][3][r]));
#pragma unroll
                for (int msk = 1; msk < 16; msk <<= 1) mx = fmaxf(mx, __shfl_xor(mx, msk));
                float mn = fmaxf(m2[rg][r], mx);
                fac[r] = exp2f(m2[rg][r] - mn);
                m2[rg][r] = mn;
                float rs = 0.f;
#pragma unroll
                for (int kf = 0; kf < 4; ++kf) {
                    float p = exp2f(s[rg][kf][r] - mn);
                    s[rg][kf][r] = p;
                    rs += p;
                }
#pragma unroll
                for (int msk = 1; msk < 16; msk <<= 1) rs += __shfl_xor(rs, msk);
                lsum[rg][r] = lsum[rg][r] * fac[r] + rs;
            }
#pragma unroll
            for (int df = 0; df < 12; ++df)
#pragma unroll
                for (int r = 0; r < 4; ++r) acc_o[rg][df][r] *= fac[r];
#pragma unroll
            for (int r = 0; r < 4; ++r) {
                int q = rg * 16 + (lane >> 4) * 4 + r;
                int xr = ((q >> 2) & 3) << 3;
#pragma unroll
                for (int kf = 0; kf < 4; ++kf)
                    lPw[q * 64 + ((kf * 16 + (lane & 15)) ^ xr)] = f2bf(s[rg][kf][r]);
            }
        }
        // O += P V
#pragma unroll
        for (int ks = 0; ks < 2; ++ks) {
            const int prow0 = (lane & 15), prow1 = 16 + (lane & 15);
            const int pcol = ks * 32 + (lane >> 4) * 8;
            bf16x8 pa0 = *(const bf16x8*)&lPw[prow0 * 64 + (pcol ^ (((prow0 >> 2) & 3) << 3))];
            bf16x8 pa1 = *(const bf16x8*)&lPw[prow1 * 64 + (pcol ^ (((prow1 >> 2) & 3) << 3))];
#pragma unroll
            for (int df = 0; df < 12; ++df) {
                const int vrow = df * 16 + (lane & 15);
                bf16x8 bv = *(const bf16x8*)&lVc[vrow * 64 + ((ks * 4 + (lane >> 4)) ^ (vrow & 7)) * 8];
                acc_o[0][df] = __builtin_amdgcn_mfma_f32_16x16x32_bf16(pa0, bv, acc_o[0][df], 0, 0, 0);
                acc_o[1][df] = __builtin_amdgcn_mfma_f32_16x16x32_bf16(pa1, bv, acc_o[1][df], 0, 0, 0);
            }
        }
    };

#pragma unroll 1
    for (int it2 = 0; it2 < 16; it2 += 2) {
        __syncthreads();                         // drains vmcnt: buf0 ready
        STAGE(lK1, lV1, it2 + 1);                // overlaps with compute below
        compute(lK0, lV0);
        __syncthreads();                         // buf1 ready
        if (it2 + 2 < 16) STAGE(lK0, lV0, it2 + 2);
        compute(lK1, lV1);
    }

    u16* dst = comb + ((size_t)(b * 1024 + qt * 256 + w * 32)) * 3072 + h * 192;
#pragma unroll
    for (int rg = 0; rg < 2; ++rg)
#pragma unroll
        for (int r = 0; r < 4; ++r) {
            int q = rg * 16 + (lane >> 4) * 4 + r;
            float invl = 1.0f / lsum[rg][r];
#pragma unroll
            for (int df = 0; df < 12; ++df)
                dst[(size_t)q * 3072 + df * 16 + (lane & 15)] = f2bf(acc_o[rg][df][r] * invl);
        }
#undef STAGE
}

// ---------------- host ----------------
extern "C" void kernel_launch(void* const* d_in, const int* in_sizes, int n_in,
                              void* d_out, int out_size, void* d_ws, size_t ws_size,
                              hipStream_t stream) {
    const float* X  = (const float*)d_in[0];   // [8,3072,1024]
    const float* W1 = (const float*)d_in[1];   // [1024,3072]
    const float* W2 = (const float*)d_in[2];   // [3072,1024]
    const float* Bb = (const float*)d_in[3];   // [1024]

    char* ws = (char*)d_ws;
    u16* Xb   = (u16*)(ws);                          // 50,331,648 B ; reused as comb
    u16* W1bT = (u16*)(ws + 50331648);               //  6,291,456 B  [3072][1024]
    u16* W2bT = (u16*)(ws + 56623104);               //  6,291,456 B  [1024][3072]
    u16* QKVb = (u16*)(ws + 62914560);               // 150,994,944 B [24576][3072]
    u16* VT   = (u16*)(ws + 213909504);              // 50,331,648 B  [128][192][1024]
    u16* comb = Xb;                                  // [8192][3072]

    cast_kernel<<<2048, 256, 0, stream>>>(X, Xb, (8 * 3072 * 1024) / 4);
    wtrans_kernel<<<dim3(3072 / 64, 1024 / 64), 256, 0, stream>>>(W1, W1bT, 1024, 3072);
    wtrans_kernel<<<dim3(1024 / 64, 3072 / 64), 256, 0, stream>>>(W2, W2bT, 3072, 1024);
    gemm_bt_kernel<false><<<(24576 / 128) * (3072 / 128), 256, 0, stream>>>(
        Xb, W1bT, QKVb, nullptr, 24576, 3072, 1024);
    vtrans_kernel<<<dim3(16, 3, 128), 256, 0, stream>>>(QKVb, VT);
    attn_kernel<<<512, 512, 0, stream>>>(QKVb, VT, comb);
    gemm_bt_kernel<true><<<(8192 / 128) * (1024 / 128), 256, 0, stream>>>(
        comb, W2bT, d_out, Bb, 8192, 1024, 3072);
}

// Round 3
// 508.347 us; speedup vs baseline: 1.4089x; 1.4089x over previous
//
#include <hip/hip_runtime.h>
#include <hip/hip_bf16.h>

typedef unsigned short u16;
using f32x4  = __attribute__((ext_vector_type(4))) float;
using bf16x8 = __attribute__((ext_vector_type(8))) short;

typedef __attribute__((address_space(1))) const void global_cvoid;
typedef __attribute__((address_space(3))) void lds_void;

__device__ __forceinline__ void async16(const u16* g, u16* l) {
    // direct global->LDS DMA, 16B per lane, LDS dest = wave-uniform base + lane*16
    __builtin_amdgcn_global_load_lds((global_cvoid*)g, (lds_void*)l, 16, 0, 0);
}

__device__ __forceinline__ u16 f2bf(float f) {
    union { float f; unsigned u; } cv; cv.f = f;
    unsigned r = cv.u + 0x7fff + ((cv.u >> 16) & 1);   // RNE
    return (u16)(r >> 16);
}

// ---------------- cast fp32 -> bf16 (vectorized, memory-bound) ----------------
__global__ __launch_bounds__(256) void cast_kernel(const float* __restrict__ src,
                                                   u16* __restrict__ dst, int n4) {
    int i = blockIdx.x * blockDim.x + threadIdx.x;
    int st = gridDim.x * blockDim.x;
    for (; i < n4; i += st) {
        float4 v = ((const float4*)src)[i];
        ushort4 o;
        o.x = f2bf(v.x); o.y = f2bf(v.y); o.z = f2bf(v.z); o.w = f2bf(v.w);
        ((ushort4*)dst)[i] = o;
    }
}

// ---------------- transpose + cast: fp32 [R][C] -> bf16 [C][R] ----------------
__global__ __launch_bounds__(256) void wtrans_kernel(const float* __restrict__ src,
                                                     u16* __restrict__ dst, int R, int C) {
    __shared__ float tile[64][68];
    int ct = blockIdx.x, rt = blockIdx.y;
    int t = threadIdx.x;
    int r = t >> 2;
    const float* s = src + (size_t)(rt * 64 + r) * C + ct * 64;
#pragma unroll
    for (int jj = 0; jj < 4; ++jj) {
        int c4 = (t & 3) + jj * 4;
        float4 v = *(const float4*)(s + c4 * 4);
        *(float4*)&tile[r][c4 * 4] = v;
    }
    __syncthreads();
    int od = t >> 2;
    u16* d = dst + (size_t)(ct * 64 + od) * R + rt * 64;
#pragma unroll
    for (int jj = 0; jj < 4; ++jj) {
        int c4 = (t & 3) + jj * 4;
        ushort4 v;
        v.x = f2bf(tile[c4 * 4 + 0][od]);
        v.y = f2bf(tile[c4 * 4 + 1][od]);
        v.z = f2bf(tile[c4 * 4 + 2][od]);
        v.w = f2bf(tile[c4 * 4 + 3][od]);
        *(ushort4*)(d + c4 * 4) = v;
    }
}

// ------------- V transpose (bf16->bf16): per (b,h) [1024][192] -> [192][1024] -------------
__global__ __launch_bounds__(256) void vtrans_kernel(const u16* __restrict__ QKV,
                                                     u16* __restrict__ VT) {
    __shared__ u16 tile[64][72];
    int kt = blockIdx.x, dt = blockIdx.y, bh = blockIdx.z;
    int b = bh >> 4, h = bh & 15;
    int t = threadIdx.x;
    int r = t >> 2;
    const u16* src = QKV + ((size_t)(b * 3072 + 2048 + kt * 64)) * 3072 + h * 192 + dt * 64;
#pragma unroll
    for (int jj = 0; jj < 4; ++jj) {
        int c4 = (t & 3) + jj * 4;
        ushort4 v = *(const ushort4*)(src + (size_t)r * 3072 + c4 * 4);
        *(ushort4*)&tile[r][c4 * 4] = v;
    }
    __syncthreads();
    int od = t >> 2;
    u16* dst = VT + ((size_t)(bh * 192 + dt * 64 + od)) * 1024 + kt * 64;
#pragma unroll
    for (int jj = 0; jj < 4; ++jj) {
        int c4 = (t & 3) + jj * 4;
        ushort4 v;
        v.x = tile[c4 * 4 + 0][od];
        v.y = tile[c4 * 4 + 1][od];
        v.z = tile[c4 * 4 + 2][od];
        v.w = tile[c4 * 4 + 3][od];
        *(ushort4*)(dst + c4 * 4) = v;
    }
}

// ---------------- 128x128 bf16 GEMM, B^T input (m97 structure) ----------------
template<bool OUT_F32>
__global__ __launch_bounds__(256, 2)
void gemm_bt_kernel(const u16* __restrict__ A, const u16* __restrict__ BT,
                    void* __restrict__ Cout, const float* __restrict__ bias,
                    int M, int N, int K) {
    __shared__ u16 lA[128 * 64];
    __shared__ u16 lB[128 * 64];
    const int t = threadIdx.x;
    const int w = t >> 6, lane = t & 63;
    const int nbx = N >> 7;
    const int nwg = gridDim.x;
    int bid = blockIdx.x;
    int cpx = nwg >> 3;
    int swz = (bid & 7) * cpx + (bid >> 3);
    const int bx = swz % nbx;
    const int by = swz / nbx;
    const size_t m0 = (size_t)by * 128, n0 = (size_t)bx * 128;

    const int lr = lane >> 3;
    const int lc = (lane & 7) * 8;
    const int wr = (w >> 1) * 64, wc = (w & 1) * 64;

    f32x4 acc[4][4] = {};

    for (int kk = 0; kk < K; kk += 64) {
        __syncthreads();
#pragma unroll
        for (int i = 0; i < 4; ++i) {
            int rr = (w * 4 + i) * 8 + lr;
            async16(A  + (m0 + rr) * (size_t)K + kk + lc, &lA[(w * 4 + i) * 512]);
            async16(BT + (n0 + rr) * (size_t)K + kk + lc, &lB[(w * 4 + i) * 512]);
        }
        __syncthreads();
#pragma unroll
        for (int ks = 0; ks < 2; ++ks) {
            bf16x8 af[4], bfv[4];
#pragma unroll
            for (int m = 0; m < 4; ++m)
                af[m] = *(const bf16x8*)&lA[(wr + m * 16 + (lane & 15)) * 64 + ks * 32 + (lane >> 4) * 8];
#pragma unroll
            for (int n = 0; n < 4; ++n)
                bfv[n] = *(const bf16x8*)&lB[(wc + n * 16 + (lane & 15)) * 64 + ks * 32 + (lane >> 4) * 8];
#pragma unroll
            for (int m = 0; m < 4; ++m)
#pragma unroll
                for (int n = 0; n < 4; ++n)
                    acc[m][n] = __builtin_amdgcn_mfma_f32_16x16x32_bf16(af[m], bfv[n], acc[m][n], 0, 0, 0);
        }
    }

    const int r0 = (lane >> 4) * 4;
    const int cl = lane & 15;
    if constexpr (OUT_F32) {
        float* C = (float*)Cout;
#pragma unroll
        for (int m = 0; m < 4; ++m) {
            size_t row = m0 + wr + m * 16 + r0;
#pragma unroll
            for (int n = 0; n < 4; ++n) {
                size_t col = n0 + wc + n * 16 + cl;
                float bv = bias[col];
#pragma unroll
                for (int r = 0; r < 4; ++r)
                    C[(row + r) * (size_t)N + col] = acc[m][n][r] + bv;
            }
        }
    } else {
        u16* C = (u16*)Cout;
#pragma unroll
        for (int m = 0; m < 4; ++m) {
            size_t row = m0 + wr + m * 16 + r0;
#pragma unroll
            for (int n = 0; n < 4; ++n) {
                size_t col = n0 + wc + n * 16 + cl;
#pragma unroll
                for (int r = 0; r < 4; ++r)
                    C[(row + r) * (size_t)N + col] = f2bf(acc[m][n][r]);
            }
        }
    }
}

// ---------------- flash attention v3 ----------------
// 256 thr (4 waves), q-tile 64 (16 rows/wave), KVBLK=64. 80 KiB LDS -> 2 blocks/CU.
// XOR-swizzled K/V/P tiles (pre-swizzled global src, linear global_load_lds dest,
// swizzled ds_read). K double-buffered prefetch; V staged under QK^T phase.
// Q fragments direct global->VGPR.
__global__ __launch_bounds__(256, 2)
void attn_kernel(const u16* __restrict__ QKV, const u16* __restrict__ VT,
                 u16* __restrict__ comb) {
    __shared__ u16 lds[40960];                 // 81920 B: K0|K1|V|P
    u16* lK0 = lds;                            // 24576 B [64][192] swz
    u16* lK1 = lds + 12288;                    // 24576 B
    u16* lV  = lds + 24576;                    // 24576 B [192][64] swz
    u16* lP  = lds + 36864;                    //  8192 B, per-wave [16][64] swz

    const int t = threadIdx.x, w = t >> 6, lane = t & 63;
    const int bid = blockIdx.x;
    const int gid = (bid & 7) * 256 + (bid >> 3);   // XCD-chunked: 16 qt-blocks of a bh share an XCD
    const int bh = gid >> 4, qt = gid & 15;
    const int b = bh >> 4, h = bh & 15;

    const u16* Qg  = QKV + ((size_t)(b * 3072 + qt * 64 + w * 16)) * 3072 + h * 192;
    const u16* Kg  = QKV + ((size_t)(b * 3072 + 1024)) * 3072 + h * 192;
    const u16* VTg = VT + (size_t)bh * 192 * 1024;

    // iteration-invariant pre-swizzled staging sources (rule #21: swz src + linear dest)
    const u16* Ksrc[6];
    const u16* Vsrc[6];
#pragma unroll
    for (int i = 0; i < 6; ++i) {
        int ch = i * 256 + t;
        int kr = ch / 24, kc = ch % 24;             // K tile: 64 rows x 24 chunks(16B)
        Ksrc[i] = Kg + (size_t)kr * 3072 + (kc ^ (kr & 7)) * 8;
        int vr = ch >> 3, vc = ch & 7;              // V tile: 192 rows x 8 chunks
        Vsrc[i] = VTg + (size_t)vr * 1024 + (vc ^ (vr & 7)) * 8;
    }

#define STAGE_K(dK, kt) do {                                                     \
    _Pragma("unroll")                                                            \
    for (int i = 0; i < 6; ++i)                                                  \
        async16(Ksrc[i] + (size_t)(kt) * 196608, (dK) + (i * 256 + w * 64) * 8); \
    } while (0)
#define STAGE_V(kt) do {                                                         \
    _Pragma("unroll")                                                            \
    for (int i = 0; i < 6; ++i)                                                  \
        async16(Vsrc[i] + (size_t)(kt) * 64, lV + (i * 256 + w * 64) * 8);       \
    } while (0)

    STAGE_K(lK0, 0);

    // Q fragments: direct global->VGPR (once; QKV rows are L2-hot)
    bf16x8 aq[6];
#pragma unroll
    for (int cs = 0; cs < 6; ++cs)
        aq[cs] = *(const bf16x8*)(Qg + (size_t)(lane & 15) * 3072 + cs * 32 + (lane >> 4) * 8);

    f32x4 acc_o[12] = {};
    float m2[4]  = {-1e30f, -1e30f, -1e30f, -1e30f};
    float lsum[4] = {0.f, 0.f, 0.f, 0.f};
    const float SC = 0.125f * 1.4426950408889634f;  // scale * log2(e)
    u16* lPw = &lP[w * 1024];

    auto tile_step = [&](int it, u16* Kc, u16* Ka) {
        __syncthreads();                        // A: K[it] ready; prev V reads done
        STAGE_V(it);                            // V latency hides under QK^T+softmax
        if (it + 1 < 16) STAGE_K(Ka, it + 1);   // K prefetch: covered by whole tile

        // S = Q K^T  (K read swizzled)
        f32x4 s[4] = {};
#pragma unroll
        for (int kf = 0; kf < 4; ++kf) {
            const int krow = kf * 16 + (lane & 15);
#pragma unroll
            for (int cs = 0; cs < 6; ++cs) {
                bf16x8 bk = *(const bf16x8*)&Kc[krow * 192 + ((cs * 4 + (lane >> 4)) ^ (krow & 7)) * 8];
                s[kf] = __builtin_amdgcn_mfma_f32_16x16x32_bf16(aq[cs], bk, s[kf], 0, 0, 0);
            }
        }
#pragma unroll
        for (int kf = 0; kf < 4; ++kf) s[kf] *= SC;

        // online softmax (rows = (lane>>4)*4+r; 16-lane reduce over k cols)
        float fac[4];
#pragma unroll
        for (int r = 0; r < 4; ++r) {
            float mx = fmaxf(fmaxf(s[0][r], s[1][r]), fmaxf(s[2][r], s[3][r]));
#pragma unroll
            for (int msk = 1; msk < 16; msk <<= 1) mx = fmaxf(mx, __shfl_xor(mx, msk));
            float mn = fmaxf(m2[r], mx);
            fac[r] = exp2f(m2[r] - mn);
            m2[r] = mn;
            float rs = 0.f;
#pragma unroll
            for (int kf = 0; kf < 4; ++kf) {
                float p = exp2f(s[kf][r] - mn);
                s[kf][r] = p;
                rs += p;
            }
#pragma unroll
            for (int msk = 1; msk < 16; msk <<= 1) rs += __shfl_xor(rs, msk);
            lsum[r] = lsum[r] * fac[r] + rs;
        }
#pragma unroll
        for (int df = 0; df < 12; ++df)
#pragma unroll
            for (int r = 0; r < 4; ++r) acc_o[df][r] *= fac[r];

        // P -> per-wave LDS [16][64], XOR-swizzled by row
#pragma unroll
        for (int r = 0; r < 4; ++r) {
            int q = (lane >> 4) * 4 + r;
            int xr = (q & 7) << 3;
#pragma unroll
            for (int kf = 0; kf < 4; ++kf)
                lPw[q * 64 + ((kf * 16 + (lane & 15)) ^ xr)] = f2bf(s[kf][r]);
        }

        __syncthreads();                        // B: V[it] staged (vmcnt drain)

        // O += P V  (P and V reads swizzled)
#pragma unroll
        for (int ks = 0; ks < 2; ++ks) {
            const int prow = lane & 15;
            const int pcol = ks * 32 + (lane >> 4) * 8;
            bf16x8 pa = *(const bf16x8*)&lPw[prow * 64 + (pcol ^ ((prow & 7) << 3))];
#pragma unroll
            for (int df = 0; df < 12; ++df) {
                const int vrow = df * 16 + (lane & 15);
                bf16x8 bv = *(const bf16x8*)&lV[vrow * 64 + ((ks * 4 + (lane >> 4)) ^ (vrow & 7)) * 8];
                acc_o[df] = __builtin_amdgcn_mfma_f32_16x16x32_bf16(pa, bv, acc_o[df], 0, 0, 0);
            }
        }
    };

#pragma unroll 1
    for (int it2 = 0; it2 < 16; it2 += 2) {
        tile_step(it2,     lK0, lK1);
        tile_step(it2 + 1, lK1, lK0);
    }

    u16* dst = comb + ((size_t)(b * 1024 + qt * 64 + w * 16)) * 3072 + h * 192;
#pragma unroll
    for (int r = 0; r < 4; ++r) {
        int q = (lane >> 4) * 4 + r;
        float invl = 1.0f / lsum[r];
#pragma unroll
        for (int df = 0; df < 12; ++df)
            dst[(size_t)q * 3072 + df * 16 + (lane & 15)] = f2bf(acc_o[df][r] * invl);
    }
#undef STAGE_K
#undef STAGE_V
}

// ---------------- host ----------------
extern "C" void kernel_launch(void* const* d_in, const int* in_sizes, int n_in,
                              void* d_out, int out_size, void* d_ws, size_t ws_size,
                              hipStream_t stream) {
    const float* X  = (const float*)d_in[0];   // [8,3072,1024]
    const float* W1 = (const float*)d_in[1];   // [1024,3072]
    const float* W2 = (const float*)d_in[2];   // [3072,1024]
    const float* Bb = (const float*)d_in[3];   // [1024]

    char* ws = (char*)d_ws;
    u16* Xb   = (u16*)(ws);                          // 50,331,648 B ; reused as comb
    u16* W1bT = (u16*)(ws + 50331648);               //  6,291,456 B  [3072][1024]
    u16* W2bT = (u16*)(ws + 56623104);               //  6,291,456 B  [1024][3072]
    u16* QKVb = (u16*)(ws + 62914560);               // 150,994,944 B [24576][3072]
    u16* VT   = (u16*)(ws + 213909504);              // 50,331,648 B  [128][192][1024]
    u16* comb = Xb;                                  // [8192][3072]

    cast_kernel<<<2048, 256, 0, stream>>>(X, Xb, (8 * 3072 * 1024) / 4);
    wtrans_kernel<<<dim3(3072 / 64, 1024 / 64), 256, 0, stream>>>(W1, W1bT, 1024, 3072);
    wtrans_kernel<<<dim3(1024 / 64, 3072 / 64), 256, 0, stream>>>(W2, W2bT, 3072, 1024);
    gemm_bt_kernel<false><<<(24576 / 128) * (3072 / 128), 256, 0, stream>>>(
        Xb, W1bT, QKVb, nullptr, 24576, 3072, 1024);
    vtrans_kernel<<<dim3(16, 3, 128), 256, 0, stream>>>(QKVb, VT);
    attn_kernel<<<2048, 256, 0, stream>>>(QKVb, VT, comb);
    gemm_bt_kernel<true><<<(8192 / 128) * (1024 / 128), 256, 0, stream>>>(
        comb, W2bT, d_out, Bb, 8192, 1024, 3072);
}